// Round 4
// baseline (1025.056 us; speedup 1.0000x reference)
//
#include <hip/hip_runtime.h>
#include <cstdint>
#include <cstddef>

#define NFEAT 256
#define NCLS  16

typedef unsigned int uint;
typedef unsigned short ushort;
typedef __attribute__((ext_vector_type(8))) short short8;
typedef __attribute__((ext_vector_type(4))) float f32x4;

__device__ inline float blo(uint u) { return __uint_as_float(u << 16); }
__device__ inline float bhi(uint u) { return __uint_as_float(u & 0xffff0000u); }
__device__ inline ushort f2bf(float f) {
    uint b = __float_as_uint(f);
    b += 0x7fffu + ((b >> 16) & 1u);
    return (ushort)(b >> 16);
}
__device__ inline uint pack2(float a, float b) {
    return (uint)f2bf(a) | ((uint)f2bf(b) << 16);
}

// ---------------------------------------------------------------------------
// Graph build
// ---------------------------------------------------------------------------
__global__ void k_count(const int* __restrict__ dst, int* __restrict__ counts, int E) {
    int i = blockIdx.x * 256 + threadIdx.x;
    if (i < E) atomicAdd(&counts[dst[i]], 1);
}

__global__ void k_dis(const int* __restrict__ counts, float* __restrict__ dis, int Nn) {
    int i = blockIdx.x * 256 + threadIdx.x;
    if (i < Nn) dis[i] = rsqrtf((float)(counts[i] + 1));
}

// parallel scan, pass 1: per-block (256-wide) sums
__global__ __launch_bounds__(256) void k_bsum(const int* __restrict__ counts,
                                              int* __restrict__ bsum, int Nn) {
    int t = threadIdx.x, b = blockIdx.x;
    int i = b * 256 + t;
    int v = (i < Nn) ? counts[i] : 0;
    __shared__ int ps[256];
    ps[t] = v;
    __syncthreads();
    for (int off = 128; off > 0; off >>= 1) {
        if (t < off) ps[t] += ps[t + off];
        __syncthreads();
    }
    if (t == 0) bsum[b] = ps[0];
}

// pass 2: single block scans up to 512 block sums -> exclusive offsets
__global__ __launch_bounds__(256) void k_bscan(const int* __restrict__ bsum,
                                               int* __restrict__ boff,
                                               int nb, int* __restrict__ rowptr, int Nn) {
    int t = threadIdx.x;
    int v0 = (2 * t < nb) ? bsum[2 * t] : 0;
    int v1 = (2 * t + 1 < nb) ? bsum[2 * t + 1] : 0;
    int s = v0 + v1;
    __shared__ int ps[256];
    ps[t] = s;
    __syncthreads();
    for (int off = 1; off < 256; off <<= 1) {
        int v = (t >= off) ? ps[t - off] : 0;
        __syncthreads();
        ps[t] += v;
        __syncthreads();
    }
    int ex = ps[t] - s;
    boff[2 * t] = ex;
    boff[2 * t + 1] = ex + v0;
    if (t == 255) rowptr[Nn] = ps[255];
}

// pass 3: per-block exclusive scan + block offset -> rowptr & cursor
__global__ __launch_bounds__(256) void k_bwrite(const int* __restrict__ counts,
                                                const int* __restrict__ boff,
                                                int* __restrict__ rowptr,
                                                int* __restrict__ cursor, int Nn) {
    int t = threadIdx.x, b = blockIdx.x;
    int i = b * 256 + t;
    int v = (i < Nn) ? counts[i] : 0;
    __shared__ int ps[256];
    ps[t] = v;
    __syncthreads();
    for (int off = 1; off < 256; off <<= 1) {
        int u = (t >= off) ? ps[t - off] : 0;
        __syncthreads();
        ps[t] += u;
        __syncthreads();
    }
    int ex = ps[t] - v + boff[b];
    if (i < Nn) {
        rowptr[i] = ex;
        cursor[i] = ex;
    }
}

// scatter edges to CSR; values are NOT stored (val[e] == dis[col[e]], looked up later)
__global__ void k_fill(const int* __restrict__ src, const int* __restrict__ dst,
                       int* __restrict__ cursor, int* __restrict__ csr_col, int E) {
    int i = blockIdx.x * 256 + threadIdx.x;
    if (i < E) {
        int s = src[i], d = dst[i];
        int pos = atomicAdd(&cursor[d], 1);
        csr_col[pos] = s;
    }
}

// ---------------------------------------------------------------------------
// small dense helpers: 256x256 @ 256x256, and vec256 @ 256x256
// ---------------------------------------------------------------------------
__global__ __launch_bounds__(256) void k_mm256(const float* __restrict__ A,
                                               const float* __restrict__ B,
                                               float* __restrict__ C) {
    int i = blockIdx.x, j = threadIdx.x;
    float acc = 0.f;
    for (int k = 0; k < 256; ++k) acc = fmaf(A[i * 256 + k], B[k * 256 + j], acc);
    C[i * 256 + j] = acc;
}

__global__ __launch_bounds__(256) void k_vm256(const float* __restrict__ v,
                                               const float* __restrict__ M,
                                               float* __restrict__ r) {
    int j = threadIdx.x;
    float acc = 0.f;
    for (int k = 0; k < 256; ++k) acc = fmaf(v[k], M[(size_t)k * 256 + j], acc);
    r[j] = acc;
}

// pack Wc (fp32 [256][256]) into MFMA B-fragment layout, bf16.
__global__ __launch_bounds__(256) void k_pack(const float* __restrict__ W,
                                              uint* __restrict__ Wp) {
    int idx = blockIdx.x * 256 + threadIdx.x;   // 32768 words
    int w = idx & 3, lane = (idx >> 2) & 63, kstep = (idx >> 8) & 7, n16 = idx >> 11;
    int n = n16 * 16 + (lane & 15);
    int k = kstep * 32 + (lane >> 4) * 8 + 2 * w;
    Wp[idx] = pack2(W[k * 256 + n], W[(k + 1) * 256 + n]);
}

// ---------------------------------------------------------------------------
// MFMA GEMM: C[M,256](bf16) = A[M,256](fp32, converted on the fly) @ Wp(bf16 frags)
// ---------------------------------------------------------------------------
__global__ __launch_bounds__(256) void gemm_mfma(const float* __restrict__ A,
                                                 const uint* __restrict__ Wp,
                                                 ushort* __restrict__ C, int M) {
    int t = threadIdx.x;
    int wv = t >> 6;
    int l = t & 63;
    int m16 = l & 15;
    int kc = l >> 4;
    int bm = blockIdx.x * 64 + wv * 16;
    int bn = blockIdx.y * 64;
    int row = bm + m16;
    bool valid = row < M;
    const float* ap = A + (size_t)(valid ? row : 0) * 256 + kc * 8;
    const short8* wp = (const short8*)Wp;
    int n16b = bn >> 4;

    f32x4 acc0 = {0.f, 0.f, 0.f, 0.f};
    f32x4 acc1 = acc0, acc2 = acc0, acc3 = acc0;

#pragma unroll
    for (int ks = 0; ks < 8; ++ks) {
        float4 fa0 = make_float4(0.f, 0.f, 0.f, 0.f), fa1 = fa0;
        if (valid) {
            fa0 = *(const float4*)(ap + ks * 32);
            fa1 = *(const float4*)(ap + ks * 32 + 4);
        }
        short8 a;
        a[0] = (short)f2bf(fa0.x); a[1] = (short)f2bf(fa0.y);
        a[2] = (short)f2bf(fa0.z); a[3] = (short)f2bf(fa0.w);
        a[4] = (short)f2bf(fa1.x); a[5] = (short)f2bf(fa1.y);
        a[6] = (short)f2bf(fa1.z); a[7] = (short)f2bf(fa1.w);
        short8 b0 = wp[((n16b + 0) * 8 + ks) * 64 + l];
        short8 b1 = wp[((n16b + 1) * 8 + ks) * 64 + l];
        short8 b2 = wp[((n16b + 2) * 8 + ks) * 64 + l];
        short8 b3 = wp[((n16b + 3) * 8 + ks) * 64 + l];
        acc0 = __builtin_amdgcn_mfma_f32_16x16x32_bf16(a, b0, acc0, 0, 0, 0);
        acc1 = __builtin_amdgcn_mfma_f32_16x16x32_bf16(a, b1, acc1, 0, 0, 0);
        acc2 = __builtin_amdgcn_mfma_f32_16x16x32_bf16(a, b2, acc2, 0, 0, 0);
        acc3 = __builtin_amdgcn_mfma_f32_16x16x32_bf16(a, b3, acc3, 0, 0, 0);
    }

    // C/D layout: col = lane&15, row = (lane>>4)*4 + reg   [m89-verified]
#pragma unroll
    for (int r = 0; r < 4; ++r) {
        int orow = bm + kc * 4 + r;
        if (orow < M) {
            ushort* cp = C + (size_t)orow * 256 + bn + m16;
            cp[0]  = f2bf(acc0[r]);
            cp[16] = f2bf(acc1[r]);
            cp[32] = f2bf(acc2[r]);
            cp[48] = f2bf(acc3[r]);
        }
    }
}

// scalar propagation: sout = A_hat * sin   (FIRST: sin == ones)
template <int FIRST>
__global__ __launch_bounds__(256) void k_svec(const float* __restrict__ sin,
                                              const int* __restrict__ rowptr,
                                              const int* __restrict__ col,
                                              const float* __restrict__ dis,
                                              float* __restrict__ sout, int Nn) {
    int d = blockIdx.x * 256 + threadIdx.x;
    if (d >= Nn) return;
    int beg = rowptr[d], end = rowptr[d + 1];
    float acc = 0.f;
    if (FIRST) {
        for (int e = beg; e < end; ++e) acc += dis[col[e]];
    } else {
        for (int e = beg; e < end; ++e) {
            int c = col[e];
            acc = fmaf(dis[c], sin[c], acc);
        }
    }
    float dd = dis[d];
    sout[d] = fmaf(dd, acc, dd * dd * (FIRST ? 1.f : sin[d]));
}

// ---------------------------------------------------------------------------
// bf16 propagation: out[d] = bf16( dis_d*sum(dis[col]*y[col]) + dis_d^2*y[d] [+rank1] )
// 1 wave per node. Lane halves (32+32) process even/odd edges; each lane owns
// 8 features via one uint4 (16B) gather; 4 edge-pairs in flight (8 gathers/wave).
// ---------------------------------------------------------------------------
template <int FINAL>
__global__ __launch_bounds__(64) void k_aggb(const uint* __restrict__ y,
                                             const int* __restrict__ rowptr,
                                             const int* __restrict__ col,
                                             const float* __restrict__ dis,
                                             const float* __restrict__ s1,
                                             const float* __restrict__ s2,
                                             const float* __restrict__ s3,
                                             const float* __restrict__ c1,
                                             const float* __restrict__ c2,
                                             const float* __restrict__ c3,
                                             const float* __restrict__ c4,
                                             uint* __restrict__ out) {
    int d = blockIdx.x;
    int l = threadIdx.x;
    int half = l >> 5;          // 0: even edges, 1: odd edges
    int q = l & 31;             // 16B chunk index within the 512B row
    const uint4* yq = (const uint4*)y + q;   // row r chunk: yq[r*32]
    int beg = rowptr[d], end = rowptr[d + 1];

    float a0 = 0.f, a1 = 0.f, a2 = 0.f, a3 = 0.f;
    float a4 = 0.f, a5 = 0.f, a6 = 0.f, a7 = 0.f;

    int e = beg + half;
    // 4 edge-pairs per iteration (this half handles e, e+2, e+4, e+6)
    for (; e + 6 < end; e += 8) {
        int cA = col[e], cB = col[e + 2], cC = col[e + 4], cD = col[e + 6];
        float vA = dis[cA], vB = dis[cB], vC = dis[cC], vD = dis[cD];
        uint4 uA = yq[(size_t)cA * 32];
        uint4 uB = yq[(size_t)cB * 32];
        uint4 uC = yq[(size_t)cC * 32];
        uint4 uD = yq[(size_t)cD * 32];
        a0 = fmaf(vA, blo(uA.x), a0); a1 = fmaf(vA, bhi(uA.x), a1);
        a2 = fmaf(vA, blo(uA.y), a2); a3 = fmaf(vA, bhi(uA.y), a3);
        a4 = fmaf(vA, blo(uA.z), a4); a5 = fmaf(vA, bhi(uA.z), a5);
        a6 = fmaf(vA, blo(uA.w), a6); a7 = fmaf(vA, bhi(uA.w), a7);
        a0 = fmaf(vB, blo(uB.x), a0); a1 = fmaf(vB, bhi(uB.x), a1);
        a2 = fmaf(vB, blo(uB.y), a2); a3 = fmaf(vB, bhi(uB.y), a3);
        a4 = fmaf(vB, blo(uB.z), a4); a5 = fmaf(vB, bhi(uB.z), a5);
        a6 = fmaf(vB, blo(uB.w), a6); a7 = fmaf(vB, bhi(uB.w), a7);
        a0 = fmaf(vC, blo(uC.x), a0); a1 = fmaf(vC, bhi(uC.x), a1);
        a2 = fmaf(vC, blo(uC.y), a2); a3 = fmaf(vC, bhi(uC.y), a3);
        a4 = fmaf(vC, blo(uC.z), a4); a5 = fmaf(vC, bhi(uC.z), a5);
        a6 = fmaf(vC, blo(uC.w), a6); a7 = fmaf(vC, bhi(uC.w), a7);
        a0 = fmaf(vD, blo(uD.x), a0); a1 = fmaf(vD, bhi(uD.x), a1);
        a2 = fmaf(vD, blo(uD.y), a2); a3 = fmaf(vD, bhi(uD.y), a3);
        a4 = fmaf(vD, blo(uD.z), a4); a5 = fmaf(vD, bhi(uD.z), a5);
        a6 = fmaf(vD, blo(uD.w), a6); a7 = fmaf(vD, bhi(uD.w), a7);
    }
    for (; e < end; e += 2) {
        int c = col[e]; float v = dis[c];
        uint4 u = yq[(size_t)c * 32];
        a0 = fmaf(v, blo(u.x), a0); a1 = fmaf(v, bhi(u.x), a1);
        a2 = fmaf(v, blo(u.y), a2); a3 = fmaf(v, bhi(u.y), a3);
        a4 = fmaf(v, blo(u.z), a4); a5 = fmaf(v, bhi(u.z), a5);
        a6 = fmaf(v, blo(u.w), a6); a7 = fmaf(v, bhi(u.w), a7);
    }
    // merge halves
    a0 += __shfl_xor(a0, 32); a1 += __shfl_xor(a1, 32);
    a2 += __shfl_xor(a2, 32); a3 += __shfl_xor(a3, 32);
    a4 += __shfl_xor(a4, 32); a5 += __shfl_xor(a5, 32);
    a6 += __shfl_xor(a6, 32); a7 += __shfl_xor(a7, 32);

    if (half != 0) return;

    float dd = dis[d];
    float d2 = dd * dd;
    uint4 us = yq[(size_t)d * 32];
    float r0 = fmaf(dd, a0, d2 * blo(us.x));
    float r1 = fmaf(dd, a1, d2 * bhi(us.x));
    float r2 = fmaf(dd, a2, d2 * blo(us.y));
    float r3 = fmaf(dd, a3, d2 * bhi(us.y));
    float r4 = fmaf(dd, a4, d2 * blo(us.z));
    float r5 = fmaf(dd, a5, d2 * bhi(us.z));
    float r6 = fmaf(dd, a6, d2 * blo(us.w));
    float r7 = fmaf(dd, a7, d2 * bhi(us.w));
    if (FINAL) {
        int fb = q * 8;
        float4 C1a = *(const float4*)(c1 + fb), C1b = *(const float4*)(c1 + fb + 4);
        float4 C2a = *(const float4*)(c2 + fb), C2b = *(const float4*)(c2 + fb + 4);
        float4 C3a = *(const float4*)(c3 + fb), C3b = *(const float4*)(c3 + fb + 4);
        float4 C4a = *(const float4*)(c4 + fb), C4b = *(const float4*)(c4 + fb + 4);
        float S1 = s1[d], S2 = s2[d], S3 = s3[d];
        r0 += S3 * C1a.x + S2 * C2a.x + S1 * C3a.x + C4a.x;
        r1 += S3 * C1a.y + S2 * C2a.y + S1 * C3a.y + C4a.y;
        r2 += S3 * C1a.z + S2 * C2a.z + S1 * C3a.z + C4a.z;
        r3 += S3 * C1a.w + S2 * C2a.w + S1 * C3a.w + C4a.w;
        r4 += S3 * C1b.x + S2 * C2b.x + S1 * C3b.x + C4b.x;
        r5 += S3 * C1b.y + S2 * C2b.y + S1 * C3b.y + C4b.y;
        r6 += S3 * C1b.z + S2 * C2b.z + S1 * C3b.z + C4b.z;
        r7 += S3 * C1b.w + S2 * C2b.w + S1 * C3b.w + C4b.w;
    }
    uint4 o;
    o.x = pack2(r0, r1);
    o.y = pack2(r2, r3);
    o.z = pack2(r4, r5);
    o.w = pack2(r6, r7);
    ((uint4*)out)[(size_t)d * 32 + q] = o;
}

// ---------------------------------------------------------------------------
// final layer: Y[M,16](f32) = relu(A[M,256](bf16)) @ W2[256,16](f32)
// ---------------------------------------------------------------------------
__global__ __launch_bounds__(256) void k_gemm16b(const uint* __restrict__ A,
                                                 const float* __restrict__ W2,
                                                 float* __restrict__ Y, int M) {
    __shared__ float Ws[256][16];
    int t = threadIdx.x;
    for (int i = t; i < 256 * 16; i += 256) Ws[i >> 4][i & 15] = W2[i];
    __syncthreads();
    int tx = t & 15, ty = t >> 4;
    int r = blockIdx.x * 16 + ty;
    if (r >= M) return;
    const uint* a = A + (size_t)r * 128;
    float acc = 0.f;
    for (int i = 0; i < 128; i += 4) {
        uint4 u = *(const uint4*)(a + i);
        float f;
        f = fmaxf(blo(u.x), 0.f); acc = fmaf(f, Ws[2 * i + 0][tx], acc);
        f = fmaxf(bhi(u.x), 0.f); acc = fmaf(f, Ws[2 * i + 1][tx], acc);
        f = fmaxf(blo(u.y), 0.f); acc = fmaf(f, Ws[2 * i + 2][tx], acc);
        f = fmaxf(bhi(u.y), 0.f); acc = fmaf(f, Ws[2 * i + 3][tx], acc);
        f = fmaxf(blo(u.z), 0.f); acc = fmaf(f, Ws[2 * i + 4][tx], acc);
        f = fmaxf(bhi(u.z), 0.f); acc = fmaf(f, Ws[2 * i + 5][tx], acc);
        f = fmaxf(blo(u.w), 0.f); acc = fmaf(f, Ws[2 * i + 6][tx], acc);
        f = fmaxf(bhi(u.w), 0.f); acc = fmaf(f, Ws[2 * i + 7][tx], acc);
    }
    Y[(size_t)r * NCLS + tx] = acc;
}

// propagation at width 16 (fp32)
__global__ __launch_bounds__(256) void k_agg16(const float* __restrict__ y16,
                                               const int* __restrict__ rowptr,
                                               const int* __restrict__ col,
                                               const float* __restrict__ dis,
                                               const float* __restrict__ b2,
                                               float* __restrict__ out, int Nn) {
    int t = threadIdx.x;
    int tx = t & 15, ty = t >> 4;
    int d = blockIdx.x * 16 + ty;
    if (d >= Nn) return;
    int beg = rowptr[d], end = rowptr[d + 1];
    float acc = 0.f;
    for (int e = beg; e < end; ++e) {
        int c = col[e];
        acc = fmaf(dis[c], y16[(size_t)c * NCLS + tx], acc);
    }
    float dd = dis[d];
    out[(size_t)d * NCLS + tx] = dd * acc + dd * dd * y16[(size_t)d * NCLS + tx] + b2[tx];
}

// ---------------------------------------------------------------------------
// softmax over axis 0
// ---------------------------------------------------------------------------
__global__ __launch_bounds__(256) void k_sm1(const float* __restrict__ z,
                                             float* __restrict__ pmax,
                                             float* __restrict__ psum, int Nn) {
    int b = blockIdx.x, t = threadIdx.x, tx = t & 15, ty = t >> 4;
    int CH = (Nn + 255) / 256;
    int r0 = b * CH, r1 = min(r0 + CH, Nn);
    __shared__ float red[16][17];
    __shared__ float gloc[16];
    float m = -3.4e38f;
    for (int r = r0 + ty; r < r1; r += 16) m = fmaxf(m, z[(size_t)r * NCLS + tx]);
    red[ty][tx] = m;
    __syncthreads();
    if (ty == 0) {
        float mm = red[0][tx];
#pragma unroll
        for (int i = 1; i < 16; ++i) mm = fmaxf(mm, red[i][tx]);
        gloc[tx] = mm;
    }
    __syncthreads();
    float g = gloc[tx];
    float s = 0.f;
    for (int r = r0 + ty; r < r1; r += 16) s += expf(z[(size_t)r * NCLS + tx] - g);
    red[ty][tx] = s;
    __syncthreads();
    if (ty == 0) {
        float ss = red[0][tx];
#pragma unroll
        for (int i = 1; i < 16; ++i) ss += red[i][tx];
        pmax[b * 16 + tx] = g;
        psum[b * 16 + tx] = ss;
    }
}

__global__ __launch_bounds__(256) void k_sm2(const float* __restrict__ pmax,
                                             const float* __restrict__ psum,
                                             float* __restrict__ g16,
                                             float* __restrict__ inv16) {
    int t = threadIdx.x, tx = t & 15, ty = t >> 4;
    __shared__ float red[16][17];
    __shared__ float gsh[16];
    float m = -3.4e38f;
    for (int b = ty; b < 256; b += 16) m = fmaxf(m, pmax[b * 16 + tx]);
    red[ty][tx] = m;
    __syncthreads();
    if (ty == 0) {
        float mm = red[0][tx];
#pragma unroll
        for (int i = 1; i < 16; ++i) mm = fmaxf(mm, red[i][tx]);
        gsh[tx] = mm;
    }
    __syncthreads();
    float g = gsh[tx];
    float s = 0.f;
    for (int b = ty; b < 256; b += 16)
        s += psum[b * 16 + tx] * expf(pmax[b * 16 + tx] - g);
    red[ty][tx] = s;
    __syncthreads();
    if (ty == 0) {
        float ss = red[0][tx];
#pragma unroll
        for (int i = 1; i < 16; ++i) ss += red[i][tx];
        g16[tx] = g;
        inv16[tx] = 1.0f / ss;
    }
}

__global__ void k_sm5(float* __restrict__ z, const float* __restrict__ g16,
                      const float* __restrict__ inv16, int total) {
    int i = blockIdx.x * 256 + threadIdx.x;
    if (i < total) {
        int c = i & 15;
        z[i] = expf(z[i] - g16[c]) * inv16[c];
    }
}

// ---------------------------------------------------------------------------
extern "C" void kernel_launch(void* const* d_in, const int* in_sizes, int n_in,
                              void* d_out, int out_size, void* d_ws, size_t ws_size,
                              hipStream_t stream) {
    const float* x  = (const float*)d_in[0];
    const int*   ei = (const int*)d_in[1];
    const float* W1 = (const float*)d_in[2];
    const float* b1 = (const float*)d_in[3];
    const float* Wi = (const float*)d_in[4];
    const float* bi = (const float*)d_in[5];
    const float* W2 = (const float*)d_in[6];
    const float* b2 = (const float*)d_in[7];
    float* out = (float*)d_out;

    int Nn = in_sizes[0] / NFEAT;   // 100000
    int E  = in_sizes[1] / 2;       // 1600000
    const int* esrc = ei;
    const int* edst = ei + E;

    char* p = (char*)d_ws;
    auto carve = [&](size_t bytes) -> char* {
        char* r = p;
        p += (bytes + 255) / 256 * 256;
        return r;
    };
    uint*  bufA    = (uint*) carve((size_t)Nn * 128 * 4);   // bf16 features
    uint*  bufB    = (uint*) carve((size_t)Nn * 128 * 4);
    int*   counts  = (int*)  carve((size_t)Nn * 4);
    int*   cursor  = (int*)  carve((size_t)Nn * 4);
    int*   rowptr  = (int*)  carve((size_t)(Nn + 1) * 4);
    float* dis     = (float*)carve((size_t)Nn * 4);
    int*   csr_col = (int*)  carve((size_t)E * 4);
    float* y16     = (float*)carve((size_t)Nn * NCLS * 4);
    float* s1      = (float*)carve((size_t)Nn * 4);
    float* s2      = (float*)carve((size_t)Nn * 4);
    float* s3      = (float*)carve((size_t)Nn * 4);
    float* WA      = (float*)carve(256 * 256 * 4);
    float* WB      = (float*)carve(256 * 256 * 4);
    float* Wc      = (float*)carve(256 * 256 * 4);
    uint*  Wp      = (uint*) carve(32768 * 4);
    float* c1      = (float*)carve(256 * 4);
    float* c2      = (float*)carve(256 * 4);
    float* c3      = (float*)carve(256 * 4);
    float* u1      = (float*)carve(256 * 4);
    float* u2      = (float*)carve(256 * 4);
    int*   bsum    = (int*)  carve(512 * 4);
    int*   boff    = (int*)  carve(512 * 4);
    float* pmax    = (float*)carve(256 * 16 * 4);
    float* psum    = (float*)carve(256 * 16 * 4);
    float* g16     = (float*)carve(16 * 4);
    float* inv16   = (float*)carve(16 * 4);

    hipMemsetAsync(counts, 0, (size_t)Nn * 4, stream);

    int gE = (E + 255) / 256;
    int gN = (Nn + 255) / 256;
    k_count<<<gE, 256, 0, stream>>>(edst, counts, E);
    k_dis<<<gN, 256, 0, stream>>>(counts, dis, Nn);
    k_bsum<<<gN, 256, 0, stream>>>(counts, bsum, Nn);
    k_bscan<<<1, 256, 0, stream>>>(bsum, boff, gN, rowptr, Nn);
    k_bwrite<<<gN, 256, 0, stream>>>(counts, boff, rowptr, cursor, Nn);
    k_fill<<<gE, 256, 0, stream>>>(esrc, edst, cursor, csr_col, E);

    // weight chain: Wc = W1 Wi^3 ; c1 = b1 Wi^3, c2 = bi Wi^2, c3 = bi Wi, c4 = bi
    k_mm256<<<256, 256, 0, stream>>>(W1, Wi, WA);
    k_mm256<<<256, 256, 0, stream>>>(WA, Wi, WB);
    k_mm256<<<256, 256, 0, stream>>>(WB, Wi, Wc);
    k_pack<<<128, 256, 0, stream>>>(Wc, Wp);
    k_vm256<<<1, 256, 0, stream>>>(bi, Wi, c3);
    k_vm256<<<1, 256, 0, stream>>>(c3, Wi, c2);
    k_vm256<<<1, 256, 0, stream>>>(b1, Wi, u1);
    k_vm256<<<1, 256, 0, stream>>>(u1, Wi, u2);
    k_vm256<<<1, 256, 0, stream>>>(u2, Wi, c1);

    // scalar propagation vectors s1 = A1, s2 = A^2 1, s3 = A^3 1
    k_svec<1><<<gN, 256, 0, stream>>>(nullptr, rowptr, csr_col, dis, s1, Nn);
    k_svec<0><<<gN, 256, 0, stream>>>(s1, rowptr, csr_col, dis, s2, Nn);
    k_svec<0><<<gN, 256, 0, stream>>>(s2, rowptr, csr_col, dis, s3, Nn);

    // y0 = x @ Wc  (bf16 out, MFMA)
    dim3 gg((Nn + 63) / 64, 4);
    gemm_mfma<<<gg, 256, 0, stream>>>(x, Wp, (ushort*)bufB, Nn);

    // h4 = A^4 y0 + rank-1 terms (in the last pass)
    k_aggb<0><<<Nn, 64, 0, stream>>>(bufB, rowptr, csr_col, dis,
                                     nullptr, nullptr, nullptr, nullptr, nullptr, nullptr, nullptr, bufA);
    k_aggb<0><<<Nn, 64, 0, stream>>>(bufA, rowptr, csr_col, dis,
                                     nullptr, nullptr, nullptr, nullptr, nullptr, nullptr, nullptr, bufB);
    k_aggb<0><<<Nn, 64, 0, stream>>>(bufB, rowptr, csr_col, dis,
                                     nullptr, nullptr, nullptr, nullptr, nullptr, nullptr, nullptr, bufA);
    k_aggb<1><<<Nn, 64, 0, stream>>>(bufA, rowptr, csr_col, dis,
                                     s1, s2, s3, c1, c2, c3, bi, bufB);

    // final: z = A(relu(h4) W2) + b2 ; softmax over nodes
    int g16b = (Nn + 15) / 16;
    k_gemm16b<<<g16b, 256, 0, stream>>>(bufB, W2, y16, Nn);
    k_agg16<<<g16b, 256, 0, stream>>>(y16, rowptr, csr_col, dis, b2, out, Nn);

    k_sm1<<<256, 256, 0, stream>>>(out, pmax, psum, Nn);
    k_sm2<<<1, 256, 0, stream>>>(pmax, psum, g16, inv16);
    k_sm5<<<(Nn * NCLS + 255) / 256, 256, 0, stream>>>(out, g16, inv16, Nn * NCLS);
}

// Round 5
// 902.474 us; speedup vs baseline: 1.1358x; 1.1358x over previous
//
#include <hip/hip_runtime.h>
#include <cstdint>
#include <cstddef>

#define NFEAT 256
#define NCLS  16

typedef unsigned int uint;
typedef unsigned short ushort;
typedef __attribute__((ext_vector_type(8))) short short8;
typedef __attribute__((ext_vector_type(4))) float f32x4;

__device__ inline float blo(uint u) { return __uint_as_float(u << 16); }
__device__ inline float bhi(uint u) { return __uint_as_float(u & 0xffff0000u); }
__device__ inline ushort f2bf(float f) {
    uint b = __float_as_uint(f);
    b += 0x7fffu + ((b >> 16) & 1u);
    return (ushort)(b >> 16);
}
__device__ inline uint pack2(float a, float b) {
    return (uint)f2bf(a) | ((uint)f2bf(b) << 16);
}

// ---------------------------------------------------------------------------
// Graph build: bucketed counting sort (bucket = dst >> 8, 391 buckets)
// ---------------------------------------------------------------------------

// coarse histogram via LDS
__global__ __launch_bounds__(256) void k_ccount(const int* __restrict__ dst,
                                                int* __restrict__ bhist, int E, int nb) {
    __shared__ int h[512];
    int t = threadIdx.x;
    for (int i = t; i < nb; i += 256) h[i] = 0;
    __syncthreads();
    for (int i = blockIdx.x * 256 + t; i < E; i += gridDim.x * 256)
        atomicAdd(&h[dst[i] >> 8], 1);
    __syncthreads();
    for (int i = t; i < nb; i += 256)
        if (h[i]) atomicAdd(&bhist[i], h[i]);
}

// single-block scan of nb (<512) bucket sizes -> boff (exclusive), gcur copy
__global__ __launch_bounds__(256) void k_cscan(const int* __restrict__ bhist,
                                               int* __restrict__ boff,
                                               int* __restrict__ gcur,
                                               int* __restrict__ rowptr,
                                               int nb, int Nn) {
    int t = threadIdx.x;
    int v0 = (2 * t < nb) ? bhist[2 * t] : 0;
    int v1 = (2 * t + 1 < nb) ? bhist[2 * t + 1] : 0;
    int s = v0 + v1;
    __shared__ int ps[256];
    ps[t] = s;
    __syncthreads();
    for (int off = 1; off < 256; off <<= 1) {
        int v = (t >= off) ? ps[t - off] : 0;
        __syncthreads();
        ps[t] += v;
        __syncthreads();
    }
    int ex = ps[t] - s;
    if (2 * t < nb)     { boff[2 * t] = ex;          gcur[2 * t] = ex; }
    if (2 * t + 1 < nb) { boff[2 * t + 1] = ex + v0; gcur[2 * t + 1] = ex + v0; }
    if (t == 255) { boff[nb] = ps[255]; rowptr[Nn] = ps[255]; }
}

// per-chunk (4096 edges) LDS-staged bucket scatter; coalesced flush
__global__ __launch_bounds__(256) void k_cfill(const int* __restrict__ src,
                                               const int* __restrict__ dst,
                                               int* __restrict__ gcur,
                                               uint2* __restrict__ ebuf, int E, int nb) {
    __shared__ int hist[400];
    __shared__ int lstart[400];
    __shared__ int gbase[400];
    __shared__ int cur[400];
    __shared__ int ps[256];
    __shared__ uint2 stg[4096];
    __shared__ ushort sb[4096];
    int t = threadIdx.x;
    int base = blockIdx.x * 4096;
    int lim = min(4096, E - base);
    for (int i = t; i < nb; i += 256) hist[i] = 0;
    __syncthreads();
    for (int k = t; k < lim; k += 256) atomicAdd(&hist[dst[base + k] >> 8], 1);
    __syncthreads();
    int v0 = (2 * t < nb) ? hist[2 * t] : 0;
    int v1 = (2 * t + 1 < nb) ? hist[2 * t + 1] : 0;
    int s = v0 + v1;
    ps[t] = s;
    __syncthreads();
    for (int off = 1; off < 256; off <<= 1) {
        int v = (t >= off) ? ps[t - off] : 0;
        __syncthreads();
        ps[t] += v;
        __syncthreads();
    }
    int ex = ps[t] - s;
    if (2 * t < nb) {
        lstart[2 * t] = ex; cur[2 * t] = ex;
        if (v0) gbase[2 * t] = atomicAdd(&gcur[2 * t], v0);
    }
    if (2 * t + 1 < nb) {
        lstart[2 * t + 1] = ex + v0; cur[2 * t + 1] = ex + v0;
        if (v1) gbase[2 * t + 1] = atomicAdd(&gcur[2 * t + 1], v1);
    }
    __syncthreads();
    for (int k = t; k < lim; k += 256) {
        int s_ = src[base + k], d_ = dst[base + k];
        int b = d_ >> 8;
        int slot = atomicAdd(&cur[b], 1);
        stg[slot] = make_uint2((uint)s_, (uint)d_);
        sb[slot] = (ushort)b;
    }
    __syncthreads();
    for (int j = t; j < lim; j += 256) {
        int b = sb[j];
        ebuf[gbase[b] + (j - lstart[b])] = stg[j];
    }
}

// per-bucket row sort: rowptr, dis, csr_col
__global__ __launch_bounds__(256) void k_rowbuild(const uint2* __restrict__ ebuf,
                                                  const int* __restrict__ boff,
                                                  int* __restrict__ rowptr,
                                                  float* __restrict__ dis,
                                                  int* __restrict__ csr_col,
                                                  int Nn, int nb) {
    int b = blockIdx.x;
    int t = threadIdx.x;
    int beg = boff[b], end = boff[b + 1];
    __shared__ int rcnt[256];
    __shared__ int rstart[256];
    __shared__ int ps[256];
    rcnt[t] = 0;
    __syncthreads();
    for (int e = beg + t; e < end; e += 256)
        atomicAdd(&rcnt[ebuf[e].y & 255], 1);
    __syncthreads();
    int v = rcnt[t];
    ps[t] = v;
    __syncthreads();
    for (int off = 1; off < 256; off <<= 1) {
        int u = (t >= off) ? ps[t - off] : 0;
        __syncthreads();
        ps[t] += u;
        __syncthreads();
    }
    int ex = ps[t] - v;
    int node = b * 256 + t;
    if (node < Nn) {
        rowptr[node] = beg + ex;
        dis[node] = rsqrtf((float)(v + 1));
    }
    rstart[t] = beg + ex;
    __syncthreads();
    rcnt[t] = 0;
    __syncthreads();
    for (int e = beg + t; e < end; e += 256) {
        uint2 ed = ebuf[e];
        int r = ed.y & 255;
        int slot = atomicAdd(&rcnt[r], 1);
        csr_col[rstart[r] + slot] = (int)ed.x;
    }
}

__global__ void k_val(const int* __restrict__ col, const float* __restrict__ dis,
                      float* __restrict__ val, int E) {
    int i = blockIdx.x * 256 + threadIdx.x;
    if (i < E) val[i] = dis[col[i]];
}

// ---------------------------------------------------------------------------
// small dense helpers: 256x256 @ 256x256, and vec256 @ 256x256
// ---------------------------------------------------------------------------
__global__ __launch_bounds__(256) void k_mm256(const float* __restrict__ A,
                                               const float* __restrict__ B,
                                               float* __restrict__ C) {
    int i = blockIdx.x, j = threadIdx.x;
    float acc = 0.f;
    for (int k = 0; k < 256; ++k) acc = fmaf(A[i * 256 + k], B[k * 256 + j], acc);
    C[i * 256 + j] = acc;
}

__global__ __launch_bounds__(256) void k_vm256(const float* __restrict__ v,
                                               const float* __restrict__ M,
                                               float* __restrict__ r) {
    int j = threadIdx.x;
    float acc = 0.f;
    for (int k = 0; k < 256; ++k) acc = fmaf(v[k], M[(size_t)k * 256 + j], acc);
    r[j] = acc;
}

// pack Wc (fp32 [256][256]) into MFMA B-fragment layout, bf16.
__global__ __launch_bounds__(256) void k_pack(const float* __restrict__ W,
                                              uint* __restrict__ Wp) {
    int idx = blockIdx.x * 256 + threadIdx.x;   // 32768 words
    int w = idx & 3, lane = (idx >> 2) & 63, kstep = (idx >> 8) & 7, n16 = idx >> 11;
    int n = n16 * 16 + (lane & 15);
    int k = kstep * 32 + (lane >> 4) * 8 + 2 * w;
    Wp[idx] = pack2(W[k * 256 + n], W[(k + 1) * 256 + n]);
}

// ---------------------------------------------------------------------------
// MFMA GEMM: C[M,256](bf16) = A[M,256](fp32, converted on the fly) @ Wp(bf16 frags)
// ---------------------------------------------------------------------------
__global__ __launch_bounds__(256) void gemm_mfma(const float* __restrict__ A,
                                                 const uint* __restrict__ Wp,
                                                 ushort* __restrict__ C, int M) {
    int t = threadIdx.x;
    int wv = t >> 6;
    int l = t & 63;
    int m16 = l & 15;
    int kc = l >> 4;
    int bm = blockIdx.x * 64 + wv * 16;
    int bn = blockIdx.y * 64;
    int row = bm + m16;
    bool valid = row < M;
    const float* ap = A + (size_t)(valid ? row : 0) * 256 + kc * 8;
    const short8* wp = (const short8*)Wp;
    int n16b = bn >> 4;

    f32x4 acc0 = {0.f, 0.f, 0.f, 0.f};
    f32x4 acc1 = acc0, acc2 = acc0, acc3 = acc0;

#pragma unroll
    for (int ks = 0; ks < 8; ++ks) {
        float4 fa0 = make_float4(0.f, 0.f, 0.f, 0.f), fa1 = fa0;
        if (valid) {
            fa0 = *(const float4*)(ap + ks * 32);
            fa1 = *(const float4*)(ap + ks * 32 + 4);
        }
        short8 a;
        a[0] = (short)f2bf(fa0.x); a[1] = (short)f2bf(fa0.y);
        a[2] = (short)f2bf(fa0.z); a[3] = (short)f2bf(fa0.w);
        a[4] = (short)f2bf(fa1.x); a[5] = (short)f2bf(fa1.y);
        a[6] = (short)f2bf(fa1.z); a[7] = (short)f2bf(fa1.w);
        short8 b0 = wp[((n16b + 0) * 8 + ks) * 64 + l];
        short8 b1 = wp[((n16b + 1) * 8 + ks) * 64 + l];
        short8 b2 = wp[((n16b + 2) * 8 + ks) * 64 + l];
        short8 b3 = wp[((n16b + 3) * 8 + ks) * 64 + l];
        acc0 = __builtin_amdgcn_mfma_f32_16x16x32_bf16(a, b0, acc0, 0, 0, 0);
        acc1 = __builtin_amdgcn_mfma_f32_16x16x32_bf16(a, b1, acc1, 0, 0, 0);
        acc2 = __builtin_amdgcn_mfma_f32_16x16x32_bf16(a, b2, acc2, 0, 0, 0);
        acc3 = __builtin_amdgcn_mfma_f32_16x16x32_bf16(a, b3, acc3, 0, 0, 0);
    }

    // C/D layout: col = lane&15, row = (lane>>4)*4 + reg   [m89-verified]
#pragma unroll
    for (int r = 0; r < 4; ++r) {
        int orow = bm + kc * 4 + r;
        if (orow < M) {
            ushort* cp = C + (size_t)orow * 256 + bn + m16;
            cp[0]  = f2bf(acc0[r]);
            cp[16] = f2bf(acc1[r]);
            cp[32] = f2bf(acc2[r]);
            cp[48] = f2bf(acc3[r]);
        }
    }
}

// scalar propagation: sout = A_hat * sin   (FIRST: sin == ones)
template <int FIRST>
__global__ __launch_bounds__(256) void k_svec(const float* __restrict__ sin,
                                              const int* __restrict__ rowptr,
                                              const int* __restrict__ col,
                                              const float* __restrict__ val,
                                              const float* __restrict__ dis,
                                              float* __restrict__ sout, int Nn) {
    int d = blockIdx.x * 256 + threadIdx.x;
    if (d >= Nn) return;
    int beg = rowptr[d], end = rowptr[d + 1];
    float acc = 0.f;
    if (FIRST) {
        for (int e = beg; e < end; ++e) acc += val[e];
    } else {
        for (int e = beg; e < end; ++e) acc = fmaf(val[e], sin[col[e]], acc);
    }
    float dd = dis[d];
    sout[d] = fmaf(dd, acc, dd * dd * (FIRST ? 1.f : sin[d]));
}

// ---------------------------------------------------------------------------
// bf16 propagation: out[d] = bf16( dis_d*sum(val*y[col]) + dis_d^2*y[d] [+rank1] )
// 64 threads = 1 wave per node; thread owns 4 features (one uint2 = 4 bf16)
// ---------------------------------------------------------------------------
template <int FINAL>
__global__ __launch_bounds__(64) void k_aggb(const uint* __restrict__ y,
                                             const int* __restrict__ rowptr,
                                             const int* __restrict__ col,
                                             const float* __restrict__ val,
                                             const float* __restrict__ dis,
                                             const float* __restrict__ s1,
                                             const float* __restrict__ s2,
                                             const float* __restrict__ s3,
                                             const float* __restrict__ c1,
                                             const float* __restrict__ c2,
                                             const float* __restrict__ c3,
                                             const float* __restrict__ c4,
                                             uint* __restrict__ out) {
    int d = blockIdx.x;
    int t = threadIdx.x;
    const uint* yt = y + 2 * t;
    int beg = rowptr[d], end = rowptr[d + 1];
    float a0 = 0.f, a1 = 0.f, a2 = 0.f, a3 = 0.f;
    int e = beg;
    for (; e + 3 < end; e += 4) {
        int   cA = col[e],     cB = col[e + 1], cC = col[e + 2], cD = col[e + 3];
        float vA = val[e],     vB = val[e + 1], vC = val[e + 2], vD = val[e + 3];
        uint2 uA = *(const uint2*)(yt + (size_t)cA * 128);
        uint2 uB = *(const uint2*)(yt + (size_t)cB * 128);
        uint2 uC = *(const uint2*)(yt + (size_t)cC * 128);
        uint2 uD = *(const uint2*)(yt + (size_t)cD * 128);
        a0 = fmaf(vA, blo(uA.x), a0); a1 = fmaf(vA, bhi(uA.x), a1);
        a2 = fmaf(vA, blo(uA.y), a2); a3 = fmaf(vA, bhi(uA.y), a3);
        a0 = fmaf(vB, blo(uB.x), a0); a1 = fmaf(vB, bhi(uB.x), a1);
        a2 = fmaf(vB, blo(uB.y), a2); a3 = fmaf(vB, bhi(uB.y), a3);
        a0 = fmaf(vC, blo(uC.x), a0); a1 = fmaf(vC, bhi(uC.x), a1);
        a2 = fmaf(vC, blo(uC.y), a2); a3 = fmaf(vC, bhi(uC.y), a3);
        a0 = fmaf(vD, blo(uD.x), a0); a1 = fmaf(vD, bhi(uD.x), a1);
        a2 = fmaf(vD, blo(uD.y), a2); a3 = fmaf(vD, bhi(uD.y), a3);
    }
    for (; e < end; ++e) {
        int c = col[e]; float v = val[e];
        uint2 u = *(const uint2*)(yt + (size_t)c * 128);
        a0 = fmaf(v, blo(u.x), a0); a1 = fmaf(v, bhi(u.x), a1);
        a2 = fmaf(v, blo(u.y), a2); a3 = fmaf(v, bhi(u.y), a3);
    }
    float dd = dis[d];
    float d2 = dd * dd;
    uint2 us = *(const uint2*)(yt + (size_t)d * 128);
    float r0 = fmaf(dd, a0, d2 * blo(us.x));
    float r1 = fmaf(dd, a1, d2 * bhi(us.x));
    float r2 = fmaf(dd, a2, d2 * blo(us.y));
    float r3 = fmaf(dd, a3, d2 * bhi(us.y));
    if (FINAL) {
        float4 C1 = *(const float4*)(c1 + 4 * t);
        float4 C2 = *(const float4*)(c2 + 4 * t);
        float4 C3 = *(const float4*)(c3 + 4 * t);
        float4 C4 = *(const float4*)(c4 + 4 * t);
        float S1 = s1[d], S2 = s2[d], S3 = s3[d];
        r0 += S3 * C1.x + S2 * C2.x + S1 * C3.x + C4.x;
        r1 += S3 * C1.y + S2 * C2.y + S1 * C3.y + C4.y;
        r2 += S3 * C1.z + S2 * C2.z + S1 * C3.z + C4.z;
        r3 += S3 * C1.w + S2 * C2.w + S1 * C3.w + C4.w;
    }
    uint2 o;
    o.x = pack2(r0, r1);
    o.y = pack2(r2, r3);
    *(uint2*)(out + (size_t)d * 128 + 2 * t) = o;
}

// ---------------------------------------------------------------------------
// final layer: Y[M,16](f32) = relu(A[M,256](bf16)) @ W2[256,16](f32)
// ---------------------------------------------------------------------------
__global__ __launch_bounds__(256) void k_gemm16b(const uint* __restrict__ A,
                                                 const float* __restrict__ W2,
                                                 float* __restrict__ Y, int M) {
    __shared__ float Ws[256][16];
    int t = threadIdx.x;
    for (int i = t; i < 256 * 16; i += 256) Ws[i >> 4][i & 15] = W2[i];
    __syncthreads();
    int tx = t & 15, ty = t >> 4;
    int r = blockIdx.x * 16 + ty;
    if (r >= M) return;
    const uint* a = A + (size_t)r * 128;
    float acc = 0.f;
    for (int i = 0; i < 128; i += 4) {
        uint4 u = *(const uint4*)(a + i);
        float f;
        f = fmaxf(blo(u.x), 0.f); acc = fmaf(f, Ws[2 * i + 0][tx], acc);
        f = fmaxf(bhi(u.x), 0.f); acc = fmaf(f, Ws[2 * i + 1][tx], acc);
        f = fmaxf(blo(u.y), 0.f); acc = fmaf(f, Ws[2 * i + 2][tx], acc);
        f = fmaxf(bhi(u.y), 0.f); acc = fmaf(f, Ws[2 * i + 3][tx], acc);
        f = fmaxf(blo(u.z), 0.f); acc = fmaf(f, Ws[2 * i + 4][tx], acc);
        f = fmaxf(bhi(u.z), 0.f); acc = fmaf(f, Ws[2 * i + 5][tx], acc);
        f = fmaxf(blo(u.w), 0.f); acc = fmaf(f, Ws[2 * i + 6][tx], acc);
        f = fmaxf(bhi(u.w), 0.f); acc = fmaf(f, Ws[2 * i + 7][tx], acc);
    }
    Y[(size_t)r * NCLS + tx] = acc;
}

// propagation at width 16 (fp32)
__global__ __launch_bounds__(256) void k_agg16(const float* __restrict__ y16,
                                               const int* __restrict__ rowptr,
                                               const int* __restrict__ col,
                                               const float* __restrict__ val,
                                               const float* __restrict__ dis,
                                               const float* __restrict__ b2,
                                               float* __restrict__ out, int Nn) {
    int t = threadIdx.x;
    int tx = t & 15, ty = t >> 4;
    int d = blockIdx.x * 16 + ty;
    if (d >= Nn) return;
    int beg = rowptr[d], end = rowptr[d + 1];
    float acc = 0.f;
    for (int e = beg; e < end; ++e)
        acc = fmaf(val[e], y16[(size_t)col[e] * NCLS + tx], acc);
    float dd = dis[d];
    out[(size_t)d * NCLS + tx] = dd * acc + dd * dd * y16[(size_t)d * NCLS + tx] + b2[tx];
}

// ---------------------------------------------------------------------------
// softmax over axis 0
// ---------------------------------------------------------------------------
__global__ __launch_bounds__(256) void k_sm1(const float* __restrict__ z,
                                             float* __restrict__ pmax,
                                             float* __restrict__ psum, int Nn) {
    int b = blockIdx.x, t = threadIdx.x, tx = t & 15, ty = t >> 4;
    int CH = (Nn + 255) / 256;
    int r0 = b * CH, r1 = min(r0 + CH, Nn);
    __shared__ float red[16][17];
    __shared__ float gloc[16];
    float m = -3.4e38f;
    for (int r = r0 + ty; r < r1; r += 16) m = fmaxf(m, z[(size_t)r * NCLS + tx]);
    red[ty][tx] = m;
    __syncthreads();
    if (ty == 0) {
        float mm = red[0][tx];
#pragma unroll
        for (int i = 1; i < 16; ++i) mm = fmaxf(mm, red[i][tx]);
        gloc[tx] = mm;
    }
    __syncthreads();
    float g = gloc[tx];
    float s = 0.f;
    for (int r = r0 + ty; r < r1; r += 16) s += expf(z[(size_t)r * NCLS + tx] - g);
    red[ty][tx] = s;
    __syncthreads();
    if (ty == 0) {
        float ss = red[0][tx];
#pragma unroll
        for (int i = 1; i < 16; ++i) ss += red[i][tx];
        pmax[b * 16 + tx] = g;
        psum[b * 16 + tx] = ss;
    }
}

__global__ __launch_bounds__(256) void k_sm2(const float* __restrict__ pmax,
                                             const float* __restrict__ psum,
                                             float* __restrict__ g16,
                                             float* __restrict__ inv16) {
    int t = threadIdx.x, tx = t & 15, ty = t >> 4;
    __shared__ float red[16][17];
    __shared__ float gsh[16];
    float m = -3.4e38f;
    for (int b = ty; b < 256; b += 16) m = fmaxf(m, pmax[b * 16 + tx]);
    red[ty][tx] = m;
    __syncthreads();
    if (ty == 0) {
        float mm = red[0][tx];
#pragma unroll
        for (int i = 1; i < 16; ++i) mm = fmaxf(mm, red[i][tx]);
        gsh[tx] = mm;
    }
    __syncthreads();
    float g = gsh[tx];
    float s = 0.f;
    for (int b = ty; b < 256; b += 16)
        s += psum[b * 16 + tx] * expf(pmax[b * 16 + tx] - g);
    red[ty][tx] = s;
    __syncthreads();
    if (ty == 0) {
        float ss = red[0][tx];
#pragma unroll
        for (int i = 1; i < 16; ++i) ss += red[i][tx];
        g16[tx] = g;
        inv16[tx] = 1.0f / ss;
    }
}

__global__ void k_sm5(float* __restrict__ z, const float* __restrict__ g16,
                      const float* __restrict__ inv16, int total) {
    int i = blockIdx.x * 256 + threadIdx.x;
    if (i < total) {
        int c = i & 15;
        z[i] = expf(z[i] - g16[c]) * inv16[c];
    }
}

// ---------------------------------------------------------------------------
extern "C" void kernel_launch(void* const* d_in, const int* in_sizes, int n_in,
                              void* d_out, int out_size, void* d_ws, size_t ws_size,
                              hipStream_t stream) {
    const float* x  = (const float*)d_in[0];
    const int*   ei = (const int*)d_in[1];
    const float* W1 = (const float*)d_in[2];
    const float* b1 = (const float*)d_in[3];
    const float* Wi = (const float*)d_in[4];
    const float* bi = (const float*)d_in[5];
    const float* W2 = (const float*)d_in[6];
    const float* b2 = (const float*)d_in[7];
    float* out = (float*)d_out;

    int Nn = in_sizes[0] / NFEAT;   // 100000
    int E  = in_sizes[1] / 2;       // 1600000
    int nb = (Nn + 255) >> 8;       // 391 coarse buckets
    const int* esrc = ei;
    const int* edst = ei + E;

    char* p = (char*)d_ws;
    auto carve = [&](size_t bytes) -> char* {
        char* r = p;
        p += (bytes + 255) / 256 * 256;
        return r;
    };
    uint*  bufA    = (uint*) carve((size_t)Nn * 128 * 4);   // bf16 features
    uint*  bufB    = (uint*) carve((size_t)Nn * 128 * 4);
    int*   rowptr  = (int*)  carve((size_t)(Nn + 1) * 4);
    float* dis     = (float*)carve((size_t)Nn * 4);
    int*   csr_col = (int*)  carve((size_t)E * 4);
    float* csr_val = (float*)carve((size_t)E * 4);
    uint2* ebuf    = (uint2*)carve((size_t)E * 8);
    int*   bhist   = (int*)  carve(512 * 4);
    int*   boff    = (int*)  carve(512 * 4);
    int*   gcur    = (int*)  carve(512 * 4);
    float* y16     = (float*)carve((size_t)Nn * NCLS * 4);
    float* s1      = (float*)carve((size_t)Nn * 4);
    float* s2      = (float*)carve((size_t)Nn * 4);
    float* s3      = (float*)carve((size_t)Nn * 4);
    float* WA      = (float*)carve(256 * 256 * 4);
    float* WB      = (float*)carve(256 * 256 * 4);
    float* Wc      = (float*)carve(256 * 256 * 4);
    uint*  Wp      = (uint*) carve(32768 * 4);
    float* c1      = (float*)carve(256 * 4);
    float* c2      = (float*)carve(256 * 4);
    float* c3      = (float*)carve(256 * 4);
    float* u1      = (float*)carve(256 * 4);
    float* u2      = (float*)carve(256 * 4);
    float* pmax    = (float*)carve(256 * 16 * 4);
    float* psum    = (float*)carve(256 * 16 * 4);
    float* g16     = (float*)carve(16 * 4);
    float* inv16   = (float*)carve(16 * 4);

    hipMemsetAsync(bhist, 0, 512 * 4, stream);

    int gE = (E + 255) / 256;
    int gN = (Nn + 255) / 256;
    int nch = (E + 4095) / 4096;

    // graph build (bucketed counting sort)
    k_ccount<<<1024, 256, 0, stream>>>(edst, bhist, E, nb);
    k_cscan<<<1, 256, 0, stream>>>(bhist, boff, gcur, rowptr, nb, Nn);
    k_cfill<<<nch, 256, 0, stream>>>(esrc, edst, gcur, ebuf, E, nb);
    k_rowbuild<<<nb, 256, 0, stream>>>(ebuf, boff, rowptr, dis, csr_col, Nn, nb);
    k_val<<<gE, 256, 0, stream>>>(csr_col, dis, csr_val, E);

    // weight chain: Wc = W1 Wi^3 ; c1 = b1 Wi^3, c2 = bi Wi^2, c3 = bi Wi, c4 = bi
    k_mm256<<<256, 256, 0, stream>>>(W1, Wi, WA);
    k_mm256<<<256, 256, 0, stream>>>(WA, Wi, WB);
    k_mm256<<<256, 256, 0, stream>>>(WB, Wi, Wc);
    k_pack<<<128, 256, 0, stream>>>(Wc, Wp);
    k_vm256<<<1, 256, 0, stream>>>(bi, Wi, c3);
    k_vm256<<<1, 256, 0, stream>>>(c3, Wi, c2);
    k_vm256<<<1, 256, 0, stream>>>(b1, Wi, u1);
    k_vm256<<<1, 256, 0, stream>>>(u1, Wi, u2);
    k_vm256<<<1, 256, 0, stream>>>(u2, Wi, c1);

    // scalar propagation vectors s1 = A1, s2 = A^2 1, s3 = A^3 1
    k_svec<1><<<gN, 256, 0, stream>>>(nullptr, rowptr, csr_col, csr_val, dis, s1, Nn);
    k_svec<0><<<gN, 256, 0, stream>>>(s1, rowptr, csr_col, csr_val, dis, s2, Nn);
    k_svec<0><<<gN, 256, 0, stream>>>(s2, rowptr, csr_col, csr_val, dis, s3, Nn);

    // y0 = x @ Wc  (bf16 out, MFMA)
    dim3 gg((Nn + 63) / 64, 4);
    gemm_mfma<<<gg, 256, 0, stream>>>(x, Wp, (ushort*)bufB, Nn);

    // h4 = A^4 y0 + rank-1 terms (in the last pass)
    k_aggb<0><<<Nn, 64, 0, stream>>>(bufB, rowptr, csr_col, csr_val, dis,
                                     nullptr, nullptr, nullptr, nullptr, nullptr, nullptr, nullptr, bufA);
    k_aggb<0><<<Nn, 64, 0, stream>>>(bufA, rowptr, csr_col, csr_val, dis,
                                     nullptr, nullptr, nullptr, nullptr, nullptr, nullptr, nullptr, bufB);
    k_aggb<0><<<Nn, 64, 0, stream>>>(bufB, rowptr, csr_col, csr_val, dis,
                                     nullptr, nullptr, nullptr, nullptr, nullptr, nullptr, nullptr, bufA);
    k_aggb<1><<<Nn, 64, 0, stream>>>(bufA, rowptr, csr_col, csr_val, dis,
                                     s1, s2, s3, c1, c2, c3, bi, bufB);

    // final: z = A(relu(h4) W2) + b2 ; softmax over nodes
    int g16b = (Nn + 15) / 16;
    k_gemm16b<<<g16b, 256, 0, stream>>>(bufB, W2, y16, Nn);
    k_agg16<<<g16b, 256, 0, stream>>>(y16, rowptr, csr_col, csr_val, dis, b2, out, Nn);

    k_sm1<<<256, 256, 0, stream>>>(out, pmax, psum, Nn);
    k_sm2<<<1, 256, 0, stream>>>(pmax, psum, g16, inv16);
    k_sm5<<<(Nn * NCLS + 255) / 256, 256, 0, stream>>>(out, g16, inv16, Nn * NCLS);
}